// Round 3
// baseline (1912.375 us; speedup 1.0000x reference)
//
#include <hip/hip_runtime.h>

typedef float f32x4 __attribute__((ext_vector_type(4)));
typedef __bf16 bf16x8 __attribute__((ext_vector_type(8)));

#define L_SEQ 577
#define BB 8
#define CC 1024
#define HH 16
#define ROWS (L_SEQ*BB)   /* 4616 */

static __device__ __forceinline__ ushort f2b(float f) {
  unsigned u = __float_as_uint(f);
  u += 0x7fffu + ((u >> 16) & 1u);
  return (ushort)(u >> 16);
}

static __device__ __forceinline__ void gld16(const void* g, void* l) {
  __builtin_amdgcn_global_load_lds((const __attribute__((address_space(1))) void*)g,
                                   (__attribute__((address_space(3))) void*)l, 16, 0, 0);
}

// ---------------- fp32 -> bf16 convert ----------------
__global__ void cvt_kernel(const float* __restrict__ src, ushort* __restrict__ dst, int n4) {
  int i = blockIdx.x * blockDim.x + threadIdx.x;
  if (i < n4) {
    float4 v = *(const float4*)(src + (size_t)i * 4);
    ushort4 o;
    o.x = f2b(v.x); o.y = f2b(v.y); o.z = f2b(v.z); o.w = f2b(v.w);
    *(ushort4*)(dst + (size_t)i * 4) = o;
  }
}

// ---------------- fused: x' = xsrc + sum(parts) + cbias; optional LN(x')->h ----------------
template<int NP, bool DOLN>
__global__ __launch_bounds__(256)
void ln_resid_kernel(const float* __restrict__ xsrc, const float* __restrict__ parts,
                     const float* __restrict__ cbias,
                     const float* __restrict__ g, const float* __restrict__ be,
                     float* __restrict__ xdst, ushort* __restrict__ hout)
{
  const int row = blockIdx.x;
  const int t = threadIdx.x;
  float4 v = *(const float4*)(xsrc + (size_t)row * CC + t * 4);
  if (NP > 0) {
    float4 c4 = *(const float4*)(cbias + t * 4);
    v.x += c4.x; v.y += c4.y; v.z += c4.z; v.w += c4.w;
    #pragma unroll
    for (int p = 0; p < NP; ++p) {
      float4 pv = *(const float4*)(parts + ((size_t)p * ROWS + row) * CC + t * 4);
      v.x += pv.x; v.y += pv.y; v.z += pv.z; v.w += pv.w;
    }
  }
  *(float4*)(xdst + (size_t)row * CC + t * 4) = v;
  if (DOLN) {
    float s  = v.x + v.y + v.z + v.w;
    float s2 = v.x*v.x + v.y*v.y + v.z*v.z + v.w*v.w;
    #pragma unroll
    for (int sd = 1; sd < 64; sd <<= 1) { s += __shfl_xor(s, sd, 64); s2 += __shfl_xor(s2, sd, 64); }
    __shared__ float ps[4], ps2[4];
    const int w = t >> 6;
    if ((t & 63) == 0) { ps[w] = s; ps2[w] = s2; }
    __syncthreads();
    s  = ps[0] + ps[1] + ps[2] + ps[3];
    s2 = ps2[0] + ps2[1] + ps2[2] + ps2[3];
    const float mean = s * (1.f / 1024.f);
    const float var  = s2 * (1.f / 1024.f) - mean * mean;
    const float rstd = rsqrtf(var + 1e-5f);
    float4 gv = *(const float4*)(g + t * 4);
    float4 bv = *(const float4*)(be + t * 4);
    ushort4 o;
    o.x = f2b((v.x - mean) * rstd * gv.x + bv.x);
    o.y = f2b((v.y - mean) * rstd * gv.y + bv.y);
    o.z = f2b((v.z - mean) * rstd * gv.z + bv.z);
    o.w = f2b((v.w - mean) * rstd * gv.w + bv.w);
    *(ushort4*)(hout + (size_t)row * CC + t * 4) = o;
  }
}

// ---------------- V transpose: qkv v-part -> vt[b][n][m] ----------------
__global__ __launch_bounds__(256)
void vt_kernel(const ushort* __restrict__ qkv, ushort* __restrict__ vt)
{
  __shared__ ushort tile[32][33];
  const int lt = blockIdx.x * 32;
  const int nt = blockIdx.y * 32;
  const int b  = blockIdx.z;
  const int tx = threadIdx.x & 31;
  const int ty = threadIdx.x >> 5;
  #pragma unroll
  for (int p = 0; p < 4; ++p) {
    int l = lt + ty + p * 8;
    ushort v = 0;
    if (l < L_SEQ) v = qkv[((size_t)l * BB + b) * 3072 + 2048 + nt + tx];
    tile[ty + p * 8][tx] = v;
  }
  __syncthreads();
  #pragma unroll
  for (int p = 0; p < 4; ++p) {
    int n = nt + ty + p * 8;
    int l = lt + tx;
    vt[((size_t)b * 1024 + n) * 608 + l] = tile[tx][ty + p * 8];
  }
}

// ---------------- attention: 4 heads/block, atomic head-avg into fp32 attnf ----------------
__global__ __launch_bounds__(256, 2)
void attn_kernel(const ushort* __restrict__ qkv,
                 const float* __restrict__ bias,
                 float* __restrict__ attnf)
{
  __shared__ float S[2][16][612];
  const int t = threadIdx.x;
  const int lane = t & 63;
  const int w = t >> 6;
  const int rb = blockIdx.x;
  const int b  = blockIdx.y;
  const int hg = blockIdx.z;
  const int r0 = rb * 16;
  float acc[37];
  #pragma unroll
  for (int k = 0; k < 37; ++k) acc[k] = 0.f;

  const int fr = lane & 15;
  const int kc = (lane >> 4) * 8;
  const int arow = min(r0 + fr, L_SEQ - 1);
  const size_t abase = ((size_t)arow * BB + b) * 3072;

  for (int hh = 0; hh < 4; ++hh) {
    const int h = hg * 4 + hh;
    const int qoff = h * 64;
    const int koff = CC + h * 64;
    bf16x8 aq0 = *(const bf16x8*)(qkv + abase + qoff + kc);
    bf16x8 aq1 = *(const bf16x8*)(qkv + abase + qoff + 32 + kc);
    bf16x8 ak0 = *(const bf16x8*)(qkv + abase + koff + kc);
    bf16x8 ak1 = *(const bf16x8*)(qkv + abase + koff + 32 + kc);
    for (int nt = w; nt < 37; nt += 4) {
      const int col = nt * 16 + fr;
      const int ncl = min(col, L_SEQ - 1);
      const size_t brow = ((size_t)ncl * BB + b) * 3072;
      bf16x8 bq0 = *(const bf16x8*)(qkv + brow + qoff + kc);
      bf16x8 bq1 = *(const bf16x8*)(qkv + brow + qoff + 32 + kc);
      bf16x8 bk0 = *(const bf16x8*)(qkv + brow + koff + kc);
      bf16x8 bk1 = *(const bf16x8*)(qkv + brow + koff + 32 + kc);
      f32x4 dq = {0.f, 0.f, 0.f, 0.f};
      f32x4 dk = {0.f, 0.f, 0.f, 0.f};
      dq = __builtin_amdgcn_mfma_f32_16x16x32_bf16(aq0, bq0, dq, 0, 0, 0);
      dq = __builtin_amdgcn_mfma_f32_16x16x32_bf16(aq1, bq1, dq, 0, 0, 0);
      dk = __builtin_amdgcn_mfma_f32_16x16x32_bf16(ak0, bk0, dk, 0, 0, 0);
      dk = __builtin_amdgcn_mfma_f32_16x16x32_bf16(ak1, bk1, dk, 0, 0, 0);
      const bool cvalid = (col < L_SEQ);
      #pragma unroll
      for (int r = 0; r < 4; ++r) {
        int row = (lane >> 4) * 4 + r;
        int l = min(r0 + row, L_SEQ - 1);
        float bs = bias[(((size_t)(b * HH + h)) * L_SEQ + l) * L_SEQ + min(col, L_SEQ - 1)];
        S[0][row][col] = cvalid ? (bs + 0.125f * dq[r]) : -1e30f;
        S[1][row][col] = cvalid ? (bs + 0.125f * dk[r]) : -1e30f;
      }
    }
    __syncthreads();
    const int rr = t >> 4;
    const int j0 = t & 15;
    #pragma unroll
    for (int v = 0; v < 2; ++v) {
      float mx = -1e30f;
      #pragma unroll
      for (int k = 0; k < 37; ++k) mx = fmaxf(mx, S[v][rr][j0 + 16 * k]);
      #pragma unroll
      for (int sd = 1; sd < 16; sd <<= 1) mx = fmaxf(mx, __shfl_xor(mx, sd, 16));
      float e[37]; float sm = 0.f;
      #pragma unroll
      for (int k = 0; k < 37; ++k) { e[k] = __expf(S[v][rr][j0 + 16 * k] - mx); sm += e[k]; }
      #pragma unroll
      for (int sd = 1; sd < 16; sd <<= 1) sm += __shfl_xor(sm, sd, 16);
      float inv = 0.03125f / sm;
      #pragma unroll
      for (int k = 0; k < 37; ++k) acc[k] += e[k] * inv;
    }
    __syncthreads();
  }
  const int rr = t >> 4;
  const int j0 = t & 15;
  const int l = r0 + rr;
  if (l < L_SEQ) {
    float* dst = attnf + (size_t)b * 608 * 608 + (size_t)l * 608;
    #pragma unroll
    for (int k = 0; k < 37; ++k)
      if (j0 + 16 * k < L_SEQ) atomicAdd(dst + j0 + 16 * k, acc[k]);
  }
}

// ---------------- AV GEMM (128-tile, small): C[gm*8+bz] = attn[bz] * vt[bz]^T ----------------
__global__ __launch_bounds__(256, 2)
void av_gemm(const ushort* __restrict__ A, int lda, int Arows, long aStride,
             const ushort* __restrict__ B, int ldb, long bStride,
             int M, int K,
             ushort* __restrict__ outb, int ldo)
{
  __shared__ __align__(16) ushort As[128 * 32];
  __shared__ __align__(16) ushort Bs[128 * 32];
  const int t = threadIdx.x;
  const int lane = t & 63;
  const int w = t >> 6;
  const int bm = blockIdx.x, bn = blockIdx.y, bz = blockIdx.z;
  const ushort* Ab = A + (long)bz * aStride;
  const ushort* Bb = B + (long)bz * bStride;
  const int srow = t >> 2;
  const int sc = (t & 3) * 8;
  const int wr = (w >> 1) * 64;
  const int wc = (w & 1) * 64;
  const int am1 = Arows - 1;
  f32x4 acc[4][4] = {};

  const int r0a = bm * 128 + srow;
  const int r0b = bn * 128 + srow;
  for (int kt = 0; kt < K; kt += 32) {
    __syncthreads();
    gld16(Ab + (size_t)min(r0a, am1) * lda + kt + sc, (void*)(As + t * 8));
    gld16(Ab + (size_t)min(r0a + 64, am1) * lda + kt + sc, (void*)(As + 2048 + t * 8));
    gld16(Bb + (size_t)r0b * ldb + kt + sc, (void*)(Bs + t * 8));
    gld16(Bb + (size_t)(r0b + 64) * ldb + kt + sc, (void*)(Bs + 2048 + t * 8));
    asm volatile("s_waitcnt vmcnt(0)" ::: "memory");
    __syncthreads();
    bf16x8 av[4], bv[4];
    const int fr = lane & 15;
    const int kc = (lane >> 4) * 8;
    #pragma unroll
    for (int m = 0; m < 4; ++m) av[m] = *(const bf16x8*)(As + (wr + m * 16 + fr) * 32 + kc);
    #pragma unroll
    for (int n = 0; n < 4; ++n) bv[n] = *(const bf16x8*)(Bs + (wc + n * 16 + fr) * 32 + kc);
    #pragma unroll
    for (int m = 0; m < 4; ++m)
      #pragma unroll
      for (int n = 0; n < 4; ++n)
        acc[m][n] = __builtin_amdgcn_mfma_f32_16x16x32_bf16(av[m], bv[n], acc[m][n], 0, 0, 0);
  }
  const int rbase = wr + (lane >> 4) * 4;
  const int cbase = wc + (lane & 15);
  #pragma unroll
  for (int n = 0; n < 4; ++n) {
    const int gn = bn * 128 + cbase + n * 16;
    #pragma unroll
    for (int m = 0; m < 4; ++m) {
      f32x4 d = acc[m][n];
      #pragma unroll
      for (int r = 0; r < 4; ++r) {
        const int gm = bm * 128 + rbase + m * 16 + r;
        if (gm < M) outb[((size_t)gm * 8 + bz) * ldo + gn] = f2b(d[r]);
      }
    }
  }
}

// ---------------- 256x256 8-phase pipelined GEMM: C = A[M,K] * B[N,K]^T ----------------
// EPI: 0=bf16+bias  1=QuickGELU bf16+bias  4=fp32 partial (z-indexed, no bias)
#define MFQ(MH, NH) \
  _Pragma("unroll") \
  for (int ks = 0; ks < 2; ++ks) \
    _Pragma("unroll") \
    for (int m = 0; m < 4; ++m) \
      _Pragma("unroll") \
      for (int n = 0; n < 2; ++n) \
        acc[(MH)*4+m][(NH)*2+n] = __builtin_amdgcn_mfma_f32_16x16x32_bf16( \
            (MH) ? Ahi[ks][m] : Alo[ks][m], (NH) ? Bhi[ks][n] : Blo[ks][n], \
            acc[(MH)*4+m][(NH)*2+n], 0, 0, 0);

#define KTILE(BOFS, KT2, MORE, DRAIN) do { \
  _Pragma("unroll") for (int ks = 0; ks < 2; ++ks) { \
    _Pragma("unroll") for (int m = 0; m < 4; ++m) Alo[ks][m] = rdA(BOFS, 0, ks, m); \
    _Pragma("unroll") for (int n = 0; n < 2; ++n) Blo[ks][n] = rdB(BOFS, 0, ks, n); \
  } \
  asm volatile("s_waitcnt lgkmcnt(8)" ::: "memory"); \
  __builtin_amdgcn_sched_barrier(0); \
  __builtin_amdgcn_s_barrier(); \
  asm volatile("s_waitcnt lgkmcnt(0)" ::: "memory"); \
  __builtin_amdgcn_sched_barrier(0); \
  __builtin_amdgcn_s_setprio(1); MFQ(0,0) __builtin_amdgcn_s_setprio(0); \
  __builtin_amdgcn_s_barrier(); \
  _Pragma("unroll") for (int ks = 0; ks < 2; ++ks) { \
    _Pragma("unroll") for (int m = 0; m < 4; ++m) Ahi[ks][m] = rdA(BOFS, 1, ks, m); \
    _Pragma("unroll") for (int n = 0; n < 2; ++n) Bhi[ks][n] = rdB(BOFS, 1, ks, n); \
  } \
  asm volatile("s_waitcnt lgkmcnt(8)" ::: "memory"); \
  __builtin_amdgcn_sched_barrier(0); \
  __builtin_amdgcn_s_barrier(); \
  asm volatile("s_waitcnt lgkmcnt(0)" ::: "memory"); \
  __builtin_amdgcn_sched_barrier(0); \
  __builtin_amdgcn_s_setprio(1); MFQ(1,1) __builtin_amdgcn_s_setprio(0); \
  __builtin_amdgcn_s_barrier(); \
  if (MORE) { stageA(KT2, BOFS, 0); stageA(KT2, BOFS, 1); } \
  __builtin_amdgcn_s_barrier(); \
  __builtin_amdgcn_s_setprio(1); MFQ(0,1) __builtin_amdgcn_s_setprio(0); \
  __builtin_amdgcn_s_barrier(); \
  if (MORE) { stageB(KT2, BOFS, 0); stageB(KT2, BOFS, 1); } \
  __builtin_amdgcn_s_barrier(); \
  __builtin_amdgcn_s_setprio(1); MFQ(1,0) __builtin_amdgcn_s_setprio(0); \
  if (MORE)       asm volatile("s_waitcnt vmcnt(6)" ::: "memory"); \
  else if (DRAIN) asm volatile("s_waitcnt vmcnt(0)" ::: "memory"); \
  __builtin_amdgcn_sched_barrier(0); \
  __builtin_amdgcn_s_barrier(); \
} while (0)

template<int EPI>
__global__ __launch_bounds__(512, 1)
void gemm8(const ushort* __restrict__ Ap, int lda, int Arows,
           const ushort* __restrict__ Bp, int ldb,
           int M, int Ksplit,
           const float* __restrict__ bias,
           ushort* __restrict__ outb, float* __restrict__ outf, int ldo)
{
  __shared__ __align__(16) char smem[131072];   // 2 bufs x (A 32KB + B 32KB)
  const int t = threadIdx.x;
  const int lane = t & 63;
  const int w = t >> 6;
  const int wm = w >> 2, wn = w & 3;
  const int bm = blockIdx.x, bn = blockIdx.y, bz = blockIdx.z;
  const int k0 = bz * Ksplit;
  const int nkt = Ksplit >> 6;
  const int iters = nkt >> 1;
  const int am1 = Arows - 1;
  const int fr = lane & 15;
  const int lq = lane >> 4;

  f32x4 acc[8][4] = {};
  bf16x8 Alo[2][4], Ahi[2][4], Blo[2][2], Bhi[2][2];

  auto stageA = [&](int kt, int bofs, int half) {
    #pragma unroll
    for (int j = 0; j < 2; ++j) {
      const int idx = t + j * 512;
      const int row = idx >> 3, cb = idx & 7;
      const int gr = min(bm * 256 + half * 128 + row, am1);
      gld16(Ap + (size_t)gr * lda + k0 + kt * 64 + ((cb ^ (row & 7)) << 3),
            smem + bofs + half * 16384 + idx * 16);
    }
  };
  auto stageB = [&](int kt, int bofs, int half) {
    #pragma unroll
    for (int j = 0; j < 2; ++j) {
      const int idx = t + j * 512;
      const int row = idx >> 3, cb = idx & 7;
      const int gr = bn * 256 + half * 128 + row;
      gld16(Bp + (size_t)gr * ldb + k0 + kt * 64 + ((cb ^ (row & 7)) << 3),
            smem + bofs + 32768 + half * 16384 + idx * 16);
    }
  };
  auto rdA = [&](int bofs, int mh, int ks, int m) -> bf16x8 {
    const int row = wm * 128 + mh * 64 + m * 16 + fr;
    const int cb  = (ks * 4 + lq) ^ (fr & 7);
    return *(const bf16x8*)(smem + bofs + row * 128 + cb * 16);
  };
  auto rdB = [&](int bofs, int nh, int ks, int n) -> bf16x8 {
    const int row = wn * 64 + nh * 32 + n * 16 + fr;
    const int cb  = (ks * 4 + lq) ^ (fr & 7);
    return *(const bf16x8*)(smem + bofs + 32768 + row * 128 + cb * 16);
  };

  // prologue: stage K-tile 0 -> buf0, K-tile 1 -> buf1
  stageA(0, 0, 0); stageA(0, 0, 1); stageB(0, 0, 0); stageB(0, 0, 1);
  stageA(1, 65536, 0); stageA(1, 65536, 1); stageB(1, 65536, 0); stageB(1, 65536, 1);
  asm volatile("s_waitcnt vmcnt(8)" ::: "memory");
  __builtin_amdgcn_sched_barrier(0);
  __builtin_amdgcn_s_barrier();

  for (int i = 0; i < iters; ++i) {
    const bool more = (i + 1 < iters);
    KTILE(0,     2 * i + 2, more, true);
    KTILE(65536, 2 * i + 3, more, false);
  }

  // epilogue
  #pragma unroll
  for (int g = 0; g < 8; ++g) {
    #pragma unroll
    for (int n = 0; n < 4; ++n) {
      const int gn = bn * 256 + wn * 64 + n * 16 + fr;
      f32x4 d = acc[g][n];
      #pragma unroll
      for (int r = 0; r < 4; ++r) {
        const int gm = bm * 256 + wm * 128 + g * 16 + lq * 4 + r;
        if (gm < M) {
          if (EPI == 0) {
            outb[(size_t)gm * ldo + gn] = f2b(d[r] + bias[gn]);
          } else if (EPI == 1) {
            float v0 = d[r] + bias[gn];
            outb[(size_t)gm * ldo + gn] = f2b(v0 / (1.f + __expf(-1.702f * v0)));
          } else {
            outf[((size_t)bz * M + gm) * ldo + gn] = d[r];
          }
        }
      }
    }
  }
}

extern "C" void kernel_launch(void* const* d_in, const int* in_sizes, int n_in,
                              void* d_out, int out_size, void* d_ws, size_t ws_size,
                              hipStream_t stream)
{
  (void)in_sizes; (void)n_in; (void)out_size; (void)ws_size;
  const float* x_in  = (const float*)d_in[0];
  const float* attb  = (const float*)d_in[1];
  const float* ln1_g = (const float*)d_in[2];
  const float* ln1_b = (const float*)d_in[3];
  const float* in_w  = (const float*)d_in[4];
  const float* in_b  = (const float*)d_in[5];
  const float* out_w = (const float*)d_in[6];
  const float* out_b = (const float*)d_in[7];
  const float* ln2_g = (const float*)d_in[8];
  const float* ln2_b = (const float*)d_in[9];
  const float* fc1_w = (const float*)d_in[10];
  const float* fc1_b = (const float*)d_in[11];
  const float* fc2_w = (const float*)d_in[12];
  const float* fc2_b = (const float*)d_in[13];
  float* x = (float*)d_out;

  char* ws = (char*)d_ws;
  size_t off = 0;
  auto alloc = [&](size_t bytes) -> void* {
    void* p = ws + off; off += (bytes + 255) & ~(size_t)255; return p;
  };
  ushort* wIn   = (ushort*)alloc(2ull * 3072 * 1024 * 2);
  ushort* wOut  = (ushort*)alloc(2ull * 1024 * 1024 * 2);
  ushort* wF1   = (ushort*)alloc(2ull * 4096 * 1024 * 2);
  ushort* wF2   = (ushort*)alloc(2ull * 4096 * 1024 * 2);
  ushort* hbuf  = (ushort*)alloc((size_t)ROWS * 1024 * 2);
  ushort* qkv   = (ushort*)alloc((size_t)ROWS * 3072 * 2);
  ushort* vt    = (ushort*)alloc((size_t)8 * 1024 * 608 * 2);
  ushort* attn  = (ushort*)alloc((size_t)8 * 608 * 608 * 2);
  float*  attnf = (float*)alloc((size_t)8 * 608 * 608 * 4);
  ushort* outlb = (ushort*)alloc((size_t)ROWS * 1024 * 2);
  float*  pbuf  = (float*)alloc((size_t)4 * ROWS * 1024 * 4);
  ushort* ubuf  = qkv;  // aliases qkv+vt region; both dead by MLP phase

  cvt_kernel<<<2 * 3072 * 1024 / 4 / 256, 256, 0, stream>>>(in_w,  wIn,  2 * 3072 * 1024 / 4);
  cvt_kernel<<<2 * 1024 * 1024 / 4 / 256, 256, 0, stream>>>(out_w, wOut, 2 * 1024 * 1024 / 4);
  cvt_kernel<<<2 * 4096 * 1024 / 4 / 256, 256, 0, stream>>>(fc1_w, wF1,  2 * 4096 * 1024 / 4);
  cvt_kernel<<<2 * 4096 * 1024 / 4 / 256, 256, 0, stream>>>(fc2_w, wF2,  2 * 4096 * 1024 / 4);
  // initial: x = x_in (copy) + LN1(layer0) -> hbuf
  ln_resid_kernel<0, true><<<ROWS, 256, 0, stream>>>(x_in, nullptr, nullptr,
      ln1_g, ln1_b, x, hbuf);

  for (int i = 0; i < 2; ++i) {
    gemm8<0><<<dim3(19, 12, 1), 512, 0, stream>>>(hbuf, 1024, ROWS,
        wIn + (size_t)i * 3072 * 1024, 1024,
        ROWS, 1024, in_b + i * 3072, qkv, nullptr, 3072);
    hipMemsetAsync(attnf, 0, (size_t)8 * 608 * 608 * 4, stream);
    attn_kernel<<<dim3(37, 8, 4), 256, 0, stream>>>(qkv, attb + (size_t)i * 128 * 577 * 577, attnf);
    vt_kernel<<<dim3(19, 32, 8), 256, 0, stream>>>(qkv, vt);
    cvt_kernel<<<8 * 608 * 608 / 4 / 256, 256, 0, stream>>>(attnf, attn, 8 * 608 * 608 / 4);
    av_gemm<<<dim3(5, 8, 8), 256, 0, stream>>>(attn, 608, 577, (long)608 * 608,
        vt, 608, (long)1024 * 608, 577, 608, outlb, 1024);
    gemm8<4><<<dim3(19, 4, 2), 512, 0, stream>>>(outlb, 1024, ROWS,
        wOut + (size_t)i * 1024 * 1024, 1024,
        ROWS, 512, nullptr, nullptr, pbuf, 1024);
    ln_resid_kernel<2, true><<<ROWS, 256, 0, stream>>>(x, pbuf, out_b + i * 1024,
        ln2_g + i * 1024, ln2_b + i * 1024, x, hbuf);
    gemm8<1><<<dim3(19, 16, 1), 512, 0, stream>>>(hbuf, 1024, ROWS,
        wF1 + (size_t)i * 4096 * 1024, 1024,
        ROWS, 1024, fc1_b + i * 4096, ubuf, nullptr, 4096);
    gemm8<4><<<dim3(19, 4, 4), 512, 0, stream>>>(ubuf, 4096, ROWS,
        wF2 + (size_t)i * 4096 * 1024, 4096,
        ROWS, 1024, nullptr, nullptr, pbuf, 1024);
    if (i == 0) {
      ln_resid_kernel<4, true><<<ROWS, 256, 0, stream>>>(x, pbuf, fc2_b,
          ln1_g + 1024, ln1_b + 1024, x, hbuf);
    } else {
      ln_resid_kernel<4, false><<<ROWS, 256, 0, stream>>>(x, pbuf, fc2_b + 1024,
          nullptr, nullptr, x, nullptr);
    }
  }
}

// Round 4
// 1029.501 us; speedup vs baseline: 1.8576x; 1.8576x over previous
//
#include <hip/hip_runtime.h>

typedef float f32x4 __attribute__((ext_vector_type(4)));
typedef __bf16 bf16x8 __attribute__((ext_vector_type(8)));

#define L_SEQ 577
#define BB 8
#define CC 1024
#define HH 16
#define ROWS (L_SEQ*BB)   /* 4616 */

static __device__ __forceinline__ ushort f2b(float f) {
  unsigned u = __float_as_uint(f);
  u += 0x7fffu + ((u >> 16) & 1u);
  return (ushort)(u >> 16);
}

static __device__ __forceinline__ void gld16(const void* g, void* l) {
  __builtin_amdgcn_global_load_lds((const __attribute__((address_space(1))) void*)g,
                                   (__attribute__((address_space(3))) void*)l, 16, 0, 0);
}

// ---------------- fp32 -> bf16 convert ----------------
__global__ void cvt_kernel(const float* __restrict__ src, ushort* __restrict__ dst, int n4) {
  int i = blockIdx.x * blockDim.x + threadIdx.x;
  if (i < n4) {
    float4 v = *(const float4*)(src + (size_t)i * 4);
    ushort4 o;
    o.x = f2b(v.x); o.y = f2b(v.y); o.z = f2b(v.z); o.w = f2b(v.w);
    *(ushort4*)(dst + (size_t)i * 4) = o;
  }
}

// ---------------- fused: x' = xsrc + sum(parts) + cbias; optional LN(x')->h ----------------
template<int NP, bool DOLN>
__global__ __launch_bounds__(256)
void ln_resid_kernel(const float* __restrict__ xsrc, const float* __restrict__ parts,
                     const float* __restrict__ cbias,
                     const float* __restrict__ g, const float* __restrict__ be,
                     float* __restrict__ xdst, ushort* __restrict__ hout)
{
  const int row = blockIdx.x;
  const int t = threadIdx.x;
  float4 v = *(const float4*)(xsrc + (size_t)row * CC + t * 4);
  if (NP > 0) {
    float4 c4 = *(const float4*)(cbias + t * 4);
    v.x += c4.x; v.y += c4.y; v.z += c4.z; v.w += c4.w;
    #pragma unroll
    for (int p = 0; p < NP; ++p) {
      float4 pv = *(const float4*)(parts + ((size_t)p * ROWS + row) * CC + t * 4);
      v.x += pv.x; v.y += pv.y; v.z += pv.z; v.w += pv.w;
    }
  }
  *(float4*)(xdst + (size_t)row * CC + t * 4) = v;
  if (DOLN) {
    float s  = v.x + v.y + v.z + v.w;
    float s2 = v.x*v.x + v.y*v.y + v.z*v.z + v.w*v.w;
    #pragma unroll
    for (int sd = 1; sd < 64; sd <<= 1) { s += __shfl_xor(s, sd, 64); s2 += __shfl_xor(s2, sd, 64); }
    __shared__ float ps[4], ps2[4];
    const int w = t >> 6;
    if ((t & 63) == 0) { ps[w] = s; ps2[w] = s2; }
    __syncthreads();
    s  = ps[0] + ps[1] + ps[2] + ps[3];
    s2 = ps2[0] + ps2[1] + ps2[2] + ps2[3];
    const float mean = s * (1.f / 1024.f);
    const float var  = s2 * (1.f / 1024.f) - mean * mean;
    const float rstd = rsqrtf(var + 1e-5f);
    float4 gv = *(const float4*)(g + t * 4);
    float4 bv = *(const float4*)(be + t * 4);
    ushort4 o;
    o.x = f2b((v.x - mean) * rstd * gv.x + bv.x);
    o.y = f2b((v.y - mean) * rstd * gv.y + bv.y);
    o.z = f2b((v.z - mean) * rstd * gv.z + bv.z);
    o.w = f2b((v.w - mean) * rstd * gv.w + bv.w);
    *(ushort4*)(hout + (size_t)row * CC + t * 4) = o;
  }
}

// ---------------- V transpose: qkv v-part -> vt[b][n][m] ----------------
__global__ __launch_bounds__(256)
void vt_kernel(const ushort* __restrict__ qkv, ushort* __restrict__ vt)
{
  __shared__ ushort tile[32][33];
  const int lt = blockIdx.x * 32;
  const int nt = blockIdx.y * 32;
  const int b  = blockIdx.z;
  const int tx = threadIdx.x & 31;
  const int ty = threadIdx.x >> 5;
  #pragma unroll
  for (int p = 0; p < 4; ++p) {
    int l = lt + ty + p * 8;
    ushort v = 0;
    if (l < L_SEQ) v = qkv[((size_t)l * BB + b) * 3072 + 2048 + nt + tx];
    tile[ty + p * 8][tx] = v;
  }
  __syncthreads();
  #pragma unroll
  for (int p = 0; p < 4; ++p) {
    int n = nt + ty + p * 8;
    int l = lt + tx;
    vt[((size_t)b * 1024 + n) * 608 + l] = tile[tx][ty + p * 8];
  }
}

// ---------------- attention: 4 heads/block, atomic head-avg into fp32 attnf ----------------
__global__ __launch_bounds__(256, 2)
void attn_kernel(const ushort* __restrict__ qkv,
                 const float* __restrict__ bias,
                 float* __restrict__ attnf)
{
  __shared__ float S[2][16][612];
  const int t = threadIdx.x;
  const int lane = t & 63;
  const int w = t >> 6;
  const int rb = blockIdx.x;
  const int b  = blockIdx.y;
  const int hg = blockIdx.z;
  const int r0 = rb * 16;
  float acc[37];
  #pragma unroll
  for (int k = 0; k < 37; ++k) acc[k] = 0.f;

  const int fr = lane & 15;
  const int kc = (lane >> 4) * 8;
  const int arow = min(r0 + fr, L_SEQ - 1);
  const size_t abase = ((size_t)arow * BB + b) * 3072;

  for (int hh = 0; hh < 4; ++hh) {
    const int h = hg * 4 + hh;
    const int qoff = h * 64;
    const int koff = CC + h * 64;
    bf16x8 aq0 = *(const bf16x8*)(qkv + abase + qoff + kc);
    bf16x8 aq1 = *(const bf16x8*)(qkv + abase + qoff + 32 + kc);
    bf16x8 ak0 = *(const bf16x8*)(qkv + abase + koff + kc);
    bf16x8 ak1 = *(const bf16x8*)(qkv + abase + koff + 32 + kc);
    for (int nt = w; nt < 37; nt += 4) {
      const int col = nt * 16 + fr;
      const int ncl = min(col, L_SEQ - 1);
      const size_t brow = ((size_t)ncl * BB + b) * 3072;
      bf16x8 bq0 = *(const bf16x8*)(qkv + brow + qoff + kc);
      bf16x8 bq1 = *(const bf16x8*)(qkv + brow + qoff + 32 + kc);
      bf16x8 bk0 = *(const bf16x8*)(qkv + brow + koff + kc);
      bf16x8 bk1 = *(const bf16x8*)(qkv + brow + koff + 32 + kc);
      f32x4 dq = {0.f, 0.f, 0.f, 0.f};
      f32x4 dk = {0.f, 0.f, 0.f, 0.f};
      dq = __builtin_amdgcn_mfma_f32_16x16x32_bf16(aq0, bq0, dq, 0, 0, 0);
      dq = __builtin_amdgcn_mfma_f32_16x16x32_bf16(aq1, bq1, dq, 0, 0, 0);
      dk = __builtin_amdgcn_mfma_f32_16x16x32_bf16(ak0, bk0, dk, 0, 0, 0);
      dk = __builtin_amdgcn_mfma_f32_16x16x32_bf16(ak1, bk1, dk, 0, 0, 0);
      const bool cvalid = (col < L_SEQ);
      #pragma unroll
      for (int r = 0; r < 4; ++r) {
        int row = (lane >> 4) * 4 + r;
        int l = min(r0 + row, L_SEQ - 1);
        float bs = bias[(((size_t)(b * HH + h)) * L_SEQ + l) * L_SEQ + min(col, L_SEQ - 1)];
        S[0][row][col] = cvalid ? (bs + 0.125f * dq[r]) : -1e30f;
        S[1][row][col] = cvalid ? (bs + 0.125f * dk[r]) : -1e30f;
      }
    }
    __syncthreads();
    const int rr = t >> 4;
    const int j0 = t & 15;
    #pragma unroll
    for (int v = 0; v < 2; ++v) {
      float mx = -1e30f;
      #pragma unroll
      for (int k = 0; k < 37; ++k) mx = fmaxf(mx, S[v][rr][j0 + 16 * k]);
      #pragma unroll
      for (int sd = 1; sd < 16; sd <<= 1) mx = fmaxf(mx, __shfl_xor(mx, sd, 16));
      float e[37]; float sm = 0.f;
      #pragma unroll
      for (int k = 0; k < 37; ++k) { e[k] = __expf(S[v][rr][j0 + 16 * k] - mx); sm += e[k]; }
      #pragma unroll
      for (int sd = 1; sd < 16; sd <<= 1) sm += __shfl_xor(sm, sd, 16);
      float inv = 0.03125f / sm;
      #pragma unroll
      for (int k = 0; k < 37; ++k) acc[k] += e[k] * inv;
    }
    __syncthreads();
  }
  const int rr = t >> 4;
  const int j0 = t & 15;
  const int l = r0 + rr;
  if (l < L_SEQ) {
    float* dst = attnf + (size_t)b * 608 * 608 + (size_t)l * 608;
    #pragma unroll
    for (int k = 0; k < 37; ++k)
      if (j0 + 16 * k < L_SEQ) atomicAdd(dst + j0 + 16 * k, acc[k]);
  }
}

// ---------------- AV GEMM (128-tile): C[gm*8+bz] = attn[bz] * vt[bz]^T ----------------
__global__ __launch_bounds__(256, 2)
void av_gemm(const ushort* __restrict__ A, int lda, int Arows, long aStride,
             const ushort* __restrict__ B, int ldb, long bStride,
             int M, int K,
             ushort* __restrict__ outb, int ldo)
{
  __shared__ __align__(16) ushort As[128 * 32];
  __shared__ __align__(16) ushort Bs[128 * 32];
  const int t = threadIdx.x;
  const int lane = t & 63;
  const int w = t >> 6;
  const int bm = blockIdx.x, bn = blockIdx.y, bz = blockIdx.z;
  const ushort* Ab = A + (long)bz * aStride;
  const ushort* Bb = B + (long)bz * bStride;
  const int srow = t >> 2;
  const int sc = (t & 3) * 8;
  const int wr = (w >> 1) * 64;
  const int wc = (w & 1) * 64;
  const int am1 = Arows - 1;
  f32x4 acc[4][4] = {};

  const int r0a = bm * 128 + srow;
  const int r0b = bn * 128 + srow;
  for (int kt = 0; kt < K; kt += 32) {
    __syncthreads();
    gld16(Ab + (size_t)min(r0a, am1) * lda + kt + sc, (void*)(As + t * 8));
    gld16(Ab + (size_t)min(r0a + 64, am1) * lda + kt + sc, (void*)(As + 2048 + t * 8));
    gld16(Bb + (size_t)r0b * ldb + kt + sc, (void*)(Bs + t * 8));
    gld16(Bb + (size_t)(r0b + 64) * ldb + kt + sc, (void*)(Bs + 2048 + t * 8));
    asm volatile("s_waitcnt vmcnt(0)" ::: "memory");
    __syncthreads();
    bf16x8 av[4], bv[4];
    const int fr = lane & 15;
    const int kc = (lane >> 4) * 8;
    #pragma unroll
    for (int m = 0; m < 4; ++m) av[m] = *(const bf16x8*)(As + (wr + m * 16 + fr) * 32 + kc);
    #pragma unroll
    for (int n = 0; n < 4; ++n) bv[n] = *(const bf16x8*)(Bs + (wc + n * 16 + fr) * 32 + kc);
    #pragma unroll
    for (int m = 0; m < 4; ++m)
      #pragma unroll
      for (int n = 0; n < 4; ++n)
        acc[m][n] = __builtin_amdgcn_mfma_f32_16x16x32_bf16(av[m], bv[n], acc[m][n], 0, 0, 0);
  }
  const int rbase = wr + (lane >> 4) * 4;
  const int cbase = wc + (lane & 15);
  #pragma unroll
  for (int n = 0; n < 4; ++n) {
    const int gn = bn * 128 + cbase + n * 16;
    #pragma unroll
    for (int m = 0; m < 4; ++m) {
      f32x4 d = acc[m][n];
      #pragma unroll
      for (int r = 0; r < 4; ++r) {
        const int gm = bm * 128 + rbase + m * 16 + r;
        if (gm < M) outb[((size_t)gm * 8 + bz) * ldo + gn] = f2b(d[r]);
      }
    }
  }
}

// ---------------- 256x256 8-phase pipelined GEMM: C = A[M,K] * B[N,K]^T ----------------
// EPI: 0=bf16+bias  1=QuickGELU bf16+bias  4=fp32 partial (z-indexed, no bias)
#define RD_A8(BOFS, MH) \
  _Pragma("unroll") for (int ks = 0; ks < 2; ++ks) \
  _Pragma("unroll") for (int m = 0; m < 4; ++m) \
    Af[ks][m] = rdA(BOFS, MH, ks, m);

#define RD_B4(BOFS, NH) \
  _Pragma("unroll") for (int ks = 0; ks < 2; ++ks) \
  _Pragma("unroll") for (int n = 0; n < 2; ++n) \
    Bf[NH][ks][n] = rdB(BOFS, NH, ks, n);

#define MFQ(MH, NH) \
  _Pragma("unroll") for (int ks = 0; ks < 2; ++ks) \
  _Pragma("unroll") for (int m = 0; m < 4; ++m) \
  _Pragma("unroll") for (int n = 0; n < 2; ++n) \
    acc[(MH)*4+m][(NH)*2+n] = __builtin_amdgcn_mfma_f32_16x16x32_bf16( \
        Af[ks][m], Bf[NH][ks][n], acc[(MH)*4+m][(NH)*2+n], 0, 0, 0);

#define BARO() \
  __builtin_amdgcn_sched_barrier(0); \
  __builtin_amdgcn_s_barrier(); \
  asm volatile("s_waitcnt lgkmcnt(0)" ::: "memory"); \
  __builtin_amdgcn_sched_barrier(0); \
  __builtin_amdgcn_s_setprio(1);

#define MF_END() \
  __builtin_amdgcn_s_setprio(0); \
  __builtin_amdgcn_sched_barrier(0); \
  __builtin_amdgcn_s_barrier();

template<int EPI>
__global__ __launch_bounds__(512, 2)
void gemm8(const ushort* __restrict__ Ap, int lda, int Arows,
           const ushort* __restrict__ Bp, int ldb,
           int M, int Ksplit,
           const float* __restrict__ bias,
           ushort* __restrict__ outb, float* __restrict__ outf, int ldo)
{
  // LDS: buf p at p*65536; A halves at +0/+16384, B halves at +32768/+49152
  __shared__ __align__(16) char smem[131072];
  const int t = threadIdx.x;
  const int lane = t & 63;
  const int w = t >> 6;
  const int wm = w >> 2, wn = w & 3;          // 2 x 4 waves
  const int bm = blockIdx.x, bn = blockIdx.y, bz = blockIdx.z;
  const int k0 = bz * Ksplit;
  const int nkt = Ksplit >> 6;
  const int iters = nkt >> 1;
  const int fr = lane & 15, lq = lane >> 4;

  f32x4 acc[8][4] = {};          // [mh*4+m][nh*2+n]
  bf16x8 Af[2][4];               // current A half: [ks][m]
  bf16x8 Bf[2][2][2];            // both B halves: [nh][ks][n]

  // per-thread staging sources (row/col-block fixed per thread; +kt*64 per tile)
  const int rowj0 = t >> 3,        cbj0 = t & 7;
  const int rowj1 = (t + 512) >> 3, cbj1 = (t + 512) & 7;
  const ushort* pA[2][2]; const ushort* pB[2][2];
  #pragma unroll
  for (int h = 0; h < 2; ++h) {
    pA[h][0] = Ap + (size_t)min(bm*256 + h*128 + rowj0, Arows-1) * lda + k0 + ((cbj0 ^ (rowj0 & 7)) << 3);
    pA[h][1] = Ap + (size_t)min(bm*256 + h*128 + rowj1, Arows-1) * lda + k0 + ((cbj1 ^ (rowj1 & 7)) << 3);
    pB[h][0] = Bp + (size_t)(bn*256 + h*128 + rowj0) * ldb + k0 + ((cbj0 ^ (rowj0 & 7)) << 3);
    pB[h][1] = Bp + (size_t)(bn*256 + h*128 + rowj1) * ldb + k0 + ((cbj1 ^ (rowj1 & 7)) << 3);
  }

  auto stA = [&](int kt, int bofs, int h) {
    gld16(pA[h][0] + kt * 64, smem + bofs + h * 16384 + t * 16);
    gld16(pA[h][1] + kt * 64, smem + bofs + h * 16384 + (t + 512) * 16);
  };
  auto stB = [&](int kt, int bofs, int h) {
    gld16(pB[h][0] + kt * 64, smem + bofs + 32768 + h * 16384 + t * 16);
    gld16(pB[h][1] + kt * 64, smem + bofs + 32768 + h * 16384 + (t + 512) * 16);
  };
  auto rdA = [&](int bofs, int mh, int ks, int m) -> bf16x8 {
    const int rl = wm * 64 + m * 16 + fr;
    const int cb = (ks * 4 + lq) ^ (fr & 7);
    return *(const bf16x8*)(smem + bofs + mh * 16384 + rl * 128 + cb * 16);
  };
  auto rdB = [&](int bofs, int nh, int ks, int n) -> bf16x8 {
    const int rl = wn * 32 + n * 16 + fr;
    const int cb = (ks * 4 + lq) ^ (fr & 7);
    return *(const bf16x8*)(smem + bofs + 32768 + nh * 16384 + rl * 128 + cb * 16);
  };

  // prologue: Ktile0 -> buf0 (A0,B0,B1,A1), Ktile1 -> buf1 (A0,B1,A1); vmcnt(6) => buf0 landed
  stA(0, 0, 0); stB(0, 0, 0); stB(0, 0, 1); stA(0, 0, 1);
  stA(1, 65536, 0); stB(1, 65536, 1); stA(1, 65536, 1);
  asm volatile("s_waitcnt vmcnt(6)" ::: "memory");
  __builtin_amdgcn_sched_barrier(0);
  __builtin_amdgcn_s_barrier();

  for (int i = 0; i < iters; ++i) {
    const bool more = (i + 1 < iters);
    const int kt2 = 2 * i + 2;
    // ---- K-tile 2i (buf0) ----
    // ph1: quadrant (0,0)
    RD_A8(0, 0) RD_B4(0, 0)
    stB(2 * i + 1, 65536, 0);                 // B0@buf1 for Ktile 2i+1 (read ph5)
    BARO(); MFQ(0, 0) MF_END();
    // ph2: (0,1)
    RD_B4(0, 1)
    if (more) stA(kt2, 0, 0);
    BARO(); MFQ(0, 1) MF_END();
    // ph3: (1,1)
    RD_A8(0, 1)
    if (more) stB(kt2, 0, 1);
    BARO(); MFQ(1, 1) MF_END();
    // ph4: (1,0) + checkpoint
    if (more) stA(kt2, 0, 1);
    BARO(); MFQ(1, 0)
    __builtin_amdgcn_s_setprio(0);
    if (more) { asm volatile("s_waitcnt vmcnt(6)" ::: "memory"); }
    else      { asm volatile("s_waitcnt vmcnt(0)" ::: "memory"); }
    __builtin_amdgcn_sched_barrier(0);
    __builtin_amdgcn_s_barrier();
    // ---- K-tile 2i+1 (buf1) ----
    // ph5: (0,0)
    RD_A8(65536, 0) RD_B4(65536, 0)
    if (more) stB(kt2, 0, 0);                 // B0@buf0 for Ktile 2i+2 (read next ph1)
    BARO(); MFQ(0, 0) MF_END();
    // ph6: (0,1)
    RD_B4(65536, 1)
    if (more) stA(2 * i + 3, 65536, 0);
    BARO(); MFQ(0, 1) MF_END();
    // ph7: (1,1)
    RD_A8(65536, 1)
    if (more) stB(2 * i + 3, 65536, 1);
    BARO(); MFQ(1, 1) MF_END();
    // ph8: (1,0) + checkpoint
    if (more) stA(2 * i + 3, 65536, 1);
    BARO(); MFQ(1, 0)
    __builtin_amdgcn_s_setprio(0);
    if (more) { asm volatile("s_waitcnt vmcnt(6)" ::: "memory"); }
    __builtin_amdgcn_sched_barrier(0);
    __builtin_amdgcn_s_barrier();
  }

  // epilogue
  #pragma unroll
  for (int mh = 0; mh < 2; ++mh)
  #pragma unroll
  for (int nh = 0; nh < 2; ++nh)
  #pragma unroll
  for (int n = 0; n < 2; ++n) {
    const int gn = bn * 256 + nh * 128 + wn * 32 + n * 16 + fr;
    const float bval = (EPI == 4) ? 0.f : bias[gn];
    #pragma unroll
    for (int m = 0; m < 4; ++m) {
      f32x4 d = acc[mh * 4 + m][nh * 2 + n];
      #pragma unroll
      for (int r = 0; r < 4; ++r) {
        const int gm = bm * 256 + mh * 128 + wm * 64 + m * 16 + lq * 4 + r;
        if (gm < M) {
          if (EPI == 0) {
            outb[(size_t)gm * ldo + gn] = f2b(d[r] + bval);
          } else if (EPI == 1) {
            float v0 = d[r] + bval;
            outb[(size_t)gm * ldo + gn] = f2b(v0 / (1.f + __expf(-1.702f * v0)));
          } else {
            outf[((size_t)bz * M + gm) * ldo + gn] = d[r];
          }
        }
      }
    }
  }
}

extern "C" void kernel_launch(void* const* d_in, const int* in_sizes, int n_in,
                              void* d_out, int out_size, void* d_ws, size_t ws_size,
                              hipStream_t stream)
{
  (void)in_sizes; (void)n_in; (void)out_size; (void)ws_size;
  const float* x_in  = (const float*)d_in[0];
  const float* attb  = (const float*)d_in[1];
  const float* ln1_g = (const float*)d_in[2];
  const float* ln1_b = (const float*)d_in[3];
  const float* in_w  = (const float*)d_in[4];
  const float* in_b  = (const float*)d_in[5];
  const float* out_w = (const float*)d_in[6];
  const float* out_b = (const float*)d_in[7];
  const float* ln2_g = (const float*)d_in[8];
  const float* ln2_b = (const float*)d_in[9];
  const float* fc1_w = (const float*)d_in[10];
  const float* fc1_b = (const float*)d_in[11];
  const float* fc2_w = (const float*)d_in[12];
  const float* fc2_b = (const float*)d_in[13];
  float* x = (float*)d_out;

  char* ws = (char*)d_ws;
  size_t off = 0;
  auto alloc = [&](size_t bytes) -> void* {
    void* p = ws + off; off += (bytes + 255) & ~(size_t)255; return p;
  };
  ushort* wIn   = (ushort*)alloc(2ull * 3072 * 1024 * 2);
  ushort* wOut  = (ushort*)alloc(2ull * 1024 * 1024 * 2);
  ushort* wF1   = (ushort*)alloc(2ull * 4096 * 1024 * 2);
  ushort* wF2   = (ushort*)alloc(2ull * 4096 * 1024 * 2);
  ushort* hbuf  = (ushort*)alloc((size_t)ROWS * 1024 * 2);
  ushort* qkv   = (ushort*)alloc((size_t)ROWS * 3072 * 2);
  ushort* vt    = (ushort*)alloc((size_t)8 * 1024 * 608 * 2);
  ushort* attn  = (ushort*)alloc((size_t)8 * 608 * 608 * 2);
  float*  attnf = (float*)alloc((size_t)8 * 608 * 608 * 4);
  ushort* outlb = (ushort*)alloc((size_t)ROWS * 1024 * 2);
  float*  pbuf  = (float*)alloc((size_t)4 * ROWS * 1024 * 4);
  ushort* ubuf  = qkv;  // aliases qkv+vt region; both dead by MLP phase

  cvt_kernel<<<2 * 3072 * 1024 / 4 / 256, 256, 0, stream>>>(in_w,  wIn,  2 * 3072 * 1024 / 4);
  cvt_kernel<<<2 * 1024 * 1024 / 4 / 256, 256, 0, stream>>>(out_w, wOut, 2 * 1024 * 1024 / 4);
  cvt_kernel<<<2 * 4096 * 1024 / 4 / 256, 256, 0, stream>>>(fc1_w, wF1,  2 * 4096 * 1024 / 4);
  cvt_kernel<<<2 * 4096 * 1024 / 4 / 256, 256, 0, stream>>>(fc2_w, wF2,  2 * 4096 * 1024 / 4);
  ln_resid_kernel<0, true><<<ROWS, 256, 0, stream>>>(x_in, nullptr, nullptr,
      ln1_g, ln1_b, x, hbuf);

  for (int i = 0; i < 2; ++i) {
    gemm8<0><<<dim3(19, 12, 1), 512, 0, stream>>>(hbuf, 1024, ROWS,
        wIn + (size_t)i * 3072 * 1024, 1024,
        ROWS, 1024, in_b + i * 3072, qkv, nullptr, 3072);
    hipMemsetAsync(attnf, 0, (size_t)8 * 608 * 608 * 4, stream);
    attn_kernel<<<dim3(37, 8, 4), 256, 0, stream>>>(qkv, attb + (size_t)i * 128 * 577 * 577, attnf);
    vt_kernel<<<dim3(19, 32, 8), 256, 0, stream>>>(qkv, vt);
    cvt_kernel<<<8 * 608 * 608 / 4 / 256, 256, 0, stream>>>(attnf, attn, 8 * 608 * 608 / 4);
    av_gemm<<<dim3(5, 8, 8), 256, 0, stream>>>(attn, 608, 577, (long)608 * 608,
        vt, 608, (long)1024 * 608, 577, 608, outlb, 1024);
    gemm8<4><<<dim3(19, 4, 2), 512, 0, stream>>>(outlb, 1024, ROWS,
        wOut + (size_t)i * 1024 * 1024, 1024,
        ROWS, 512, nullptr, nullptr, pbuf, 1024);
    ln_resid_kernel<2, true><<<ROWS, 256, 0, stream>>>(x, pbuf, out_b + i * 1024,
        ln2_g + i * 1024, ln2_b + i * 1024, x, hbuf);
    gemm8<1><<<dim3(19, 16, 1), 512, 0, stream>>>(hbuf, 1024, ROWS,
        wF1 + (size_t)i * 4096 * 1024, 1024,
        ROWS, 1024, fc1_b + i * 4096, ubuf, nullptr, 4096);
    gemm8<4><<<dim3(19, 4, 4), 512, 0, stream>>>(ubuf, 4096, ROWS,
        wF2 + (size_t)i * 4096 * 1024, 4096,
        ROWS, 1024, nullptr, nullptr, pbuf, 1024);
    if (i == 0) {
      ln_resid_kernel<4, true><<<ROWS, 256, 0, stream>>>(x, pbuf, fc2_b,
          ln1_g + 1024, ln1_b + 1024, x, hbuf);
    } else {
      ln_resid_kernel<4, false><<<ROWS, 256, 0, stream>>>(x, pbuf, fc2_b + 1024,
          nullptr, nullptr, x, nullptr);
    }
  }
}

// Round 5
// 975.107 us; speedup vs baseline: 1.9612x; 1.0558x over previous
//
#include <hip/hip_runtime.h>

typedef float f32x4 __attribute__((ext_vector_type(4)));
typedef __bf16 bf16x8 __attribute__((ext_vector_type(8)));

#define L_SEQ 577
#define BB 8
#define CC 1024
#define HH 16
#define ROWS (L_SEQ*BB)   /* 4616 */

static __device__ __forceinline__ ushort f2b(float f) {
  unsigned u = __float_as_uint(f);
  u += 0x7fffu + ((u >> 16) & 1u);
  return (ushort)(u >> 16);
}

static __device__ __forceinline__ void gld16(const void* g, void* l) {
  __builtin_amdgcn_global_load_lds((const __attribute__((address_space(1))) void*)g,
                                   (__attribute__((address_space(3))) void*)l, 16, 0, 0);
}

// ---------------- fp32 -> bf16 convert, 4 segments in one launch ----------------
__global__ void cvt4_kernel(const float* __restrict__ s0, ushort* __restrict__ d0, int n0,
                            const float* __restrict__ s1, ushort* __restrict__ d1, int n1,
                            const float* __restrict__ s2, ushort* __restrict__ d2, int n2,
                            const float* __restrict__ s3, ushort* __restrict__ d3, int n3)
{
  int i = blockIdx.x * blockDim.x + threadIdx.x;
  const float* src; ushort* dst;
  if (i < n0)                { src = s0; dst = d0; }
  else if ((i -= n0) < n1)   { src = s1; dst = d1; }
  else if ((i -= n1) < n2)   { src = s2; dst = d2; }
  else if ((i -= n2) < n3)   { src = s3; dst = d3; }
  else return;
  float4 v = *(const float4*)(src + (size_t)i * 4);
  ushort4 o;
  o.x = f2b(v.x); o.y = f2b(v.y); o.z = f2b(v.z); o.w = f2b(v.w);
  *(ushort4*)(dst + (size_t)i * 4) = o;
}

// ---------------- fused: x' = xsrc + sum(parts) + cbias; optional LN(x')->h ----------------
template<int NP, bool DOLN>
__global__ __launch_bounds__(256)
void ln_resid_kernel(const float* __restrict__ xsrc, const float* __restrict__ parts,
                     const float* __restrict__ cbias,
                     const float* __restrict__ g, const float* __restrict__ be,
                     float* __restrict__ xdst, ushort* __restrict__ hout)
{
  const int row = blockIdx.x;
  const int t = threadIdx.x;
  float4 v = *(const float4*)(xsrc + (size_t)row * CC + t * 4);
  if (NP > 0) {
    float4 c4 = *(const float4*)(cbias + t * 4);
    v.x += c4.x; v.y += c4.y; v.z += c4.z; v.w += c4.w;
    #pragma unroll
    for (int p = 0; p < NP; ++p) {
      float4 pv = *(const float4*)(parts + ((size_t)p * ROWS + row) * CC + t * 4);
      v.x += pv.x; v.y += pv.y; v.z += pv.z; v.w += pv.w;
    }
  }
  *(float4*)(xdst + (size_t)row * CC + t * 4) = v;
  if (DOLN) {
    float s  = v.x + v.y + v.z + v.w;
    float s2 = v.x*v.x + v.y*v.y + v.z*v.z + v.w*v.w;
    #pragma unroll
    for (int sd = 1; sd < 64; sd <<= 1) { s += __shfl_xor(s, sd, 64); s2 += __shfl_xor(s2, sd, 64); }
    __shared__ float ps[4], ps2[4];
    const int w = t >> 6;
    if ((t & 63) == 0) { ps[w] = s; ps2[w] = s2; }
    __syncthreads();
    s  = ps[0] + ps[1] + ps[2] + ps[3];
    s2 = ps2[0] + ps2[1] + ps2[2] + ps2[3];
    const float mean = s * (1.f / 1024.f);
    const float var  = s2 * (1.f / 1024.f) - mean * mean;
    const float rstd = rsqrtf(var + 1e-5f);
    float4 gv = *(const float4*)(g + t * 4);
    float4 bv = *(const float4*)(be + t * 4);
    ushort4 o;
    o.x = f2b((v.x - mean) * rstd * gv.x + bv.x);
    o.y = f2b((v.y - mean) * rstd * gv.y + bv.y);
    o.z = f2b((v.z - mean) * rstd * gv.z + bv.z);
    o.w = f2b((v.w - mean) * rstd * gv.w + bv.w);
    *(ushort4*)(hout + (size_t)row * CC + t * 4) = o;
  }
}

// ---------------- V transpose: qkv v-part -> vt[b][n][m] ----------------
__global__ __launch_bounds__(256)
void vt_kernel(const ushort* __restrict__ qkv, ushort* __restrict__ vt)
{
  __shared__ ushort tile[32][33];
  const int lt = blockIdx.x * 32;
  const int nt = blockIdx.y * 32;
  const int b  = blockIdx.z;
  const int tx = threadIdx.x & 31;
  const int ty = threadIdx.x >> 5;
  #pragma unroll
  for (int p = 0; p < 4; ++p) {
    int l = lt + ty + p * 8;
    ushort v = 0;
    if (l < L_SEQ) v = qkv[((size_t)l * BB + b) * 3072 + 2048 + nt + tx];
    tile[ty + p * 8][tx] = v;
  }
  __syncthreads();
  #pragma unroll
  for (int p = 0; p < 4; ++p) {
    int n = nt + ty + p * 8;
    int l = lt + tx;
    vt[((size_t)b * 1024 + n) * 608 + l] = tile[tx][ty + p * 8];
  }
}

// ---------------- attention: 4 heads/block, bf16 partial per head-group ----------------
__global__ __launch_bounds__(256, 2)
void attn_kernel(const ushort* __restrict__ qkv,
                 const float* __restrict__ bias,
                 ushort* __restrict__ attnp)      // [4][8][608][608] bf16 partials
{
  __shared__ float S[2][16][612];
  const int t = threadIdx.x;
  const int lane = t & 63;
  const int w = t >> 6;
  const int rb = blockIdx.x;
  const int b  = blockIdx.y;
  const int hg = blockIdx.z;
  const int r0 = rb * 16;
  float acc[37];
  #pragma unroll
  for (int k = 0; k < 37; ++k) acc[k] = 0.f;

  const int fr = lane & 15;
  const int lq = lane >> 4;
  const int kc = lq * 8;
  const int arow = min(r0 + fr, L_SEQ - 1);
  const size_t abase = ((size_t)arow * BB + b) * 3072;

  for (int hh = 0; hh < 4; ++hh) {
    const int h = hg * 4 + hh;
    const int qoff = h * 64;
    const int koff = CC + h * 64;
    bf16x8 aq0 = *(const bf16x8*)(qkv + abase + qoff + kc);
    bf16x8 aq1 = *(const bf16x8*)(qkv + abase + qoff + 32 + kc);
    bf16x8 ak0 = *(const bf16x8*)(qkv + abase + koff + kc);
    bf16x8 ak1 = *(const bf16x8*)(qkv + abase + koff + 32 + kc);
    const float* bprow[4];
    #pragma unroll
    for (int r = 0; r < 4; ++r) {
      const int l = min(r0 + lq * 4 + r, L_SEQ - 1);
      bprow[r] = bias + (((size_t)(b * HH + h)) * L_SEQ + l) * L_SEQ;
    }
    // software pipeline: prefetch B-fragments + bias one nt-iteration ahead
    bf16x8 nq0, nq1, nk0, nk1;
    float nbs[4];
    {
      const int ncl = min(w * 16 + fr, L_SEQ - 1);
      const size_t brow = ((size_t)ncl * BB + b) * 3072;
      nq0 = *(const bf16x8*)(qkv + brow + qoff + kc);
      nq1 = *(const bf16x8*)(qkv + brow + qoff + 32 + kc);
      nk0 = *(const bf16x8*)(qkv + brow + koff + kc);
      nk1 = *(const bf16x8*)(qkv + brow + koff + 32 + kc);
      #pragma unroll
      for (int r = 0; r < 4; ++r) nbs[r] = bprow[r][ncl];
    }
    for (int nt = w; nt < 37; nt += 4) {
      bf16x8 cq0 = nq0, cq1 = nq1, ck0 = nk0, ck1 = nk1;
      float cbs[4];
      #pragma unroll
      for (int r = 0; r < 4; ++r) cbs[r] = nbs[r];
      const int nxt = nt + 4;
      if (nxt < 37) {
        const int ncl = min(nxt * 16 + fr, L_SEQ - 1);
        const size_t brow = ((size_t)ncl * BB + b) * 3072;
        nq0 = *(const bf16x8*)(qkv + brow + qoff + kc);
        nq1 = *(const bf16x8*)(qkv + brow + qoff + 32 + kc);
        nk0 = *(const bf16x8*)(qkv + brow + koff + kc);
        nk1 = *(const bf16x8*)(qkv + brow + koff + 32 + kc);
        #pragma unroll
        for (int r = 0; r < 4; ++r) nbs[r] = bprow[r][ncl];
      }
      f32x4 dq = {0.f, 0.f, 0.f, 0.f};
      f32x4 dk = {0.f, 0.f, 0.f, 0.f};
      dq = __builtin_amdgcn_mfma_f32_16x16x32_bf16(aq0, cq0, dq, 0, 0, 0);
      dq = __builtin_amdgcn_mfma_f32_16x16x32_bf16(aq1, cq1, dq, 0, 0, 0);
      dk = __builtin_amdgcn_mfma_f32_16x16x32_bf16(ak0, ck0, dk, 0, 0, 0);
      dk = __builtin_amdgcn_mfma_f32_16x16x32_bf16(ak1, ck1, dk, 0, 0, 0);
      const int col = nt * 16 + fr;
      const bool cvalid = (col < L_SEQ);
      #pragma unroll
      for (int r = 0; r < 4; ++r) {
        const int row = lq * 4 + r;
        S[0][row][col] = cvalid ? (cbs[r] + 0.125f * dq[r]) : -1e30f;
        S[1][row][col] = cvalid ? (cbs[r] + 0.125f * dk[r]) : -1e30f;
      }
    }
    __syncthreads();
    const int rr = t >> 4;
    const int j0 = t & 15;
    #pragma unroll
    for (int v = 0; v < 2; ++v) {
      float mx = -1e30f;
      #pragma unroll
      for (int k = 0; k < 37; ++k) mx = fmaxf(mx, S[v][rr][j0 + 16 * k]);
      #pragma unroll
      for (int sd = 1; sd < 16; sd <<= 1) mx = fmaxf(mx, __shfl_xor(mx, sd, 16));
      float e[37]; float sm = 0.f;
      #pragma unroll
      for (int k = 0; k < 37; ++k) { e[k] = __expf(S[v][rr][j0 + 16 * k] - mx); sm += e[k]; }
      #pragma unroll
      for (int sd = 1; sd < 16; sd <<= 1) sm += __shfl_xor(sm, sd, 16);
      float inv = 0.03125f / sm;
      #pragma unroll
      for (int k = 0; k < 37; ++k) acc[k] += e[k] * inv;
    }
    __syncthreads();
  }
  const int rr = t >> 4;
  const int j0 = t & 15;
  const int l = r0 + rr;
  if (l < L_SEQ) {
    ushort* dstp = attnp + ((size_t)hg * 8 + b) * 608 * 608 + (size_t)l * 608;
    #pragma unroll
    for (int k = 0; k < 37; ++k) dstp[j0 + 16 * k] = f2b(acc[k]);
  }
}

// ---------------- combine 4 bf16 partials -> bf16 attn, zero pad ----------------
__global__ __launch_bounds__(256)
void attn_combine(const ushort* __restrict__ attnp, ushort* __restrict__ attn)
{
  const int t = threadIdx.x;
  if (t >= 152) return;
  const int l = blockIdx.x;
  const int b = blockIdx.y;
  const int c0 = t * 4;
  const size_t base = ((size_t)b * 608 + l) * 608 + c0;
  const size_t hs = (size_t)8 * 608 * 608;
  float s[4] = {0.f, 0.f, 0.f, 0.f};
  #pragma unroll
  for (int p = 0; p < 4; ++p) {
    ushort4 v = *(const ushort4*)(attnp + p * hs + base);
    s[0] += __uint_as_float((unsigned)v.x << 16);
    s[1] += __uint_as_float((unsigned)v.y << 16);
    s[2] += __uint_as_float((unsigned)v.z << 16);
    s[3] += __uint_as_float((unsigned)v.w << 16);
  }
  ushort4 o;
  const bool lv = (l < L_SEQ);
  o.x = (lv && c0 + 0 < L_SEQ) ? f2b(s[0]) : (ushort)0;
  o.y = (lv && c0 + 1 < L_SEQ) ? f2b(s[1]) : (ushort)0;
  o.z = (lv && c0 + 2 < L_SEQ) ? f2b(s[2]) : (ushort)0;
  o.w = (lv && c0 + 3 < L_SEQ) ? f2b(s[3]) : (ushort)0;
  *(ushort4*)(attn + base) = o;
}

// ---------------- AV GEMM (128-tile): C[gm*8+bz] = attn[bz] * vt[bz]^T ----------------
__global__ __launch_bounds__(256, 2)
void av_gemm(const ushort* __restrict__ A, int lda, int Arows, long aStride,
             const ushort* __restrict__ B, int ldb, long bStride,
             int M, int K,
             ushort* __restrict__ outb, int ldo)
{
  __shared__ __align__(16) ushort As[128 * 32];
  __shared__ __align__(16) ushort Bs[128 * 32];
  const int t = threadIdx.x;
  const int lane = t & 63;
  const int w = t >> 6;
  const int bm = blockIdx.x, bn = blockIdx.y, bz = blockIdx.z;
  const ushort* Ab = A + (long)bz * aStride;
  const ushort* Bb = B + (long)bz * bStride;
  const int srow = t >> 2;
  const int sc = (t & 3) * 8;
  const int wr = (w >> 1) * 64;
  const int wc = (w & 1) * 64;
  const int am1 = Arows - 1;
  f32x4 acc[4][4] = {};

  const int r0a = bm * 128 + srow;
  const int r0b = bn * 128 + srow;
  for (int kt = 0; kt < K; kt += 32) {
    __syncthreads();
    gld16(Ab + (size_t)min(r0a, am1) * lda + kt + sc, (void*)(As + t * 8));
    gld16(Ab + (size_t)min(r0a + 64, am1) * lda + kt + sc, (void*)(As + 2048 + t * 8));
    gld16(Bb + (size_t)r0b * ldb + kt + sc, (void*)(Bs + t * 8));
    gld16(Bb + (size_t)(r0b + 64) * ldb + kt + sc, (void*)(Bs + 2048 + t * 8));
    asm volatile("s_waitcnt vmcnt(0)" ::: "memory");
    __syncthreads();
    bf16x8 av[4], bv[4];
    const int fr = lane & 15;
    const int kc = (lane >> 4) * 8;
    #pragma unroll
    for (int m = 0; m < 4; ++m) av[m] = *(const bf16x8*)(As + (wr + m * 16 + fr) * 32 + kc);
    #pragma unroll
    for (int n = 0; n < 4; ++n) bv[n] = *(const bf16x8*)(Bs + (wc + n * 16 + fr) * 32 + kc);
    #pragma unroll
    for (int m = 0; m < 4; ++m)
      #pragma unroll
      for (int n = 0; n < 4; ++n)
        acc[m][n] = __builtin_amdgcn_mfma_f32_16x16x32_bf16(av[m], bv[n], acc[m][n], 0, 0, 0);
  }
  const int rbase = wr + (lane >> 4) * 4;
  const int cbase = wc + (lane & 15);
  #pragma unroll
  for (int n = 0; n < 4; ++n) {
    const int gn = bn * 128 + cbase + n * 16;
    #pragma unroll
    for (int m = 0; m < 4; ++m) {
      f32x4 d = acc[m][n];
      #pragma unroll
      for (int r = 0; r < 4; ++r) {
        const int gm = bm * 128 + rbase + m * 16 + r;
        if (gm < M) outb[((size_t)gm * 8 + bz) * ldo + gn] = f2b(d[r]);
      }
    }
  }
}

// ---------------- 256x256 8-phase pipelined GEMM: C = A[M,K] * B[N,K]^T ----------------
// EPI: 0=bf16+bias  1=QuickGELU bf16+bias  4=fp32 partial (z-indexed, no bias)
#define RD_A8(BOFS, MH) \
  _Pragma("unroll") for (int ks = 0; ks < 2; ++ks) \
  _Pragma("unroll") for (int m = 0; m < 4; ++m) \
    Af[ks][m] = rdA(BOFS, MH, ks, m);

#define RD_B4(BOFS, NH) \
  _Pragma("unroll") for (int ks = 0; ks < 2; ++ks) \
  _Pragma("unroll") for (int n = 0; n < 2; ++n) \
    Bf[NH][ks][n] = rdB(BOFS, NH, ks, n);

#define MFQ(MH, NH) \
  _Pragma("unroll") for (int ks = 0; ks < 2; ++ks) \
  _Pragma("unroll") for (int m = 0; m < 4; ++m) \
  _Pragma("unroll") for (int n = 0; n < 2; ++n) \
    acc[(MH)*4+m][(NH)*2+n] = __builtin_amdgcn_mfma_f32_16x16x32_bf16( \
        Af[ks][m], Bf[NH][ks][n], acc[(MH)*4+m][(NH)*2+n], 0, 0, 0);

#define BARO() \
  __builtin_amdgcn_sched_barrier(0); \
  __builtin_amdgcn_s_barrier(); \
  asm volatile("s_waitcnt lgkmcnt(0)" ::: "memory"); \
  __builtin_amdgcn_sched_barrier(0); \
  __builtin_amdgcn_s_setprio(1);

#define MF_END() \
  __builtin_amdgcn_s_setprio(0); \
  __builtin_amdgcn_sched_barrier(0); \
  __builtin_amdgcn_s_barrier();

template<int EPI>
__global__ __launch_bounds__(512, 2)
void gemm8(const ushort* __restrict__ Ap, int lda, int Arows,
           const ushort* __restrict__ Bp, int ldb,
           int M, int Ksplit,
           const float* __restrict__ bias,
           ushort* __restrict__ outb, float* __restrict__ outf, int ldo)
{
  // LDS: buf p at p*65536; A halves at +0/+16384, B halves at +32768/+49152
  __shared__ __align__(16) char smem[131072];
  const int t = threadIdx.x;
  const int lane = t & 63;
  const int w = t >> 6;
  const int wm = w >> 2, wn = w & 3;          // 2 x 4 waves
  // bijective XCD-chunked swizzle of the (bm,bn) grid (m204)
  const int gx = gridDim.x;
  const int nwg = gx * gridDim.y;
  int id = blockIdx.y * gx + blockIdx.x;
  {
    const int q8 = nwg >> 3, r8 = nwg & 7;
    const int xcd = id & 7, pos = id >> 3;
    id = (xcd < r8 ? xcd * (q8 + 1) : r8 * (q8 + 1) + (xcd - r8) * q8) + pos;
  }
  const int bm = id % gx, bn = id / gx;
  const int bz = blockIdx.z;
  const int k0 = bz * Ksplit;
  const int iters = Ksplit >> 7;
  const int fr = lane & 15, lq = lane >> 4;

  f32x4 acc[8][4] = {};          // [mh*4+m][nh*2+n]
  bf16x8 Af[2][4];               // current A half: [ks][m]
  bf16x8 Bf[2][2][2];            // both B halves: [nh][ks][n]

  const int rowj0 = t >> 3,        cbj0 = t & 7;
  const int rowj1 = (t + 512) >> 3, cbj1 = (t + 512) & 7;
  const ushort* pA[2][2]; const ushort* pB[2][2];
  #pragma unroll
  for (int h = 0; h < 2; ++h) {
    pA[h][0] = Ap + (size_t)min(bm*256 + h*128 + rowj0, Arows-1) * lda + k0 + ((cbj0 ^ (rowj0 & 7)) << 3);
    pA[h][1] = Ap + (size_t)min(bm*256 + h*128 + rowj1, Arows-1) * lda + k0 + ((cbj1 ^ (rowj1 & 7)) << 3);
    pB[h][0] = Bp + (size_t)(bn*256 + h*128 + rowj0) * ldb + k0 + ((cbj0 ^ (rowj0 & 7)) << 3);
    pB[h][1] = Bp + (size_t)(bn*256 + h*128 + rowj1) * ldb + k0 + ((cbj1 ^ (rowj1 & 7)) << 3);
  }

  auto stA = [&](int kt, int bofs, int h) {
    gld16(pA[h][0] + kt * 64, smem + bofs + h * 16384 + t * 16);
    gld16(pA[h][1] + kt * 64, smem + bofs + h * 16384 + (t + 512) * 16);
  };
  auto stB = [&](int kt, int bofs, int h) {
    gld16(pB[h][0] + kt * 64, smem + bofs + 32768 + h * 16384 + t * 16);
    gld16(pB[h][1] + kt * 64, smem + bofs + 32768 + h * 16384 + (t + 512) * 16);
  };
  auto rdA = [&](int bofs, int mh, int ks, int m) -> bf16x8 {
    const int rl = wm * 64 + m * 16 + fr;
    const int cb = (ks * 4 + lq) ^ (fr & 7);
    return *(const bf16x8*)(smem + bofs + mh * 16384 + rl * 128 + cb * 16);
  };
  auto rdB = [&](int bofs, int nh, int ks, int n) -> bf16x8 {
    const int rl = wn * 32 + n * 16 + fr;
    const int cb = (ks * 4 + lq) ^ (fr & 7);
    return *(const bf16x8*)(smem + bofs + 32768 + nh * 16384 + rl * 128 + cb * 16);
  };

  // prologue: Ktile0 -> buf0 (A0,B0,B1,A1), Ktile1 -> buf1 (A0,B1,A1); vmcnt(6) => buf0 landed
  stA(0, 0, 0); stB(0, 0, 0); stB(0, 0, 1); stA(0, 0, 1);
  stA(1, 65536, 0); stB(1, 65536, 1); stA(1, 65536, 1);
  asm volatile("s_waitcnt vmcnt(6)" ::: "memory");
  __builtin_amdgcn_sched_barrier(0);
  __builtin_amdgcn_s_barrier();

  for (int i = 0; i < iters; ++i) {
    const bool more = (i + 1 < iters);
    const int kt2 = 2 * i + 2;
    // ---- K-tile 2i (buf0) ----
    RD_A8(0, 0) RD_B4(0, 0)
    stB(2 * i + 1, 65536, 0);
    BARO(); MFQ(0, 0) MF_END();
    RD_B4(0, 1)
    if (more) stA(kt2, 0, 0);
    BARO(); MFQ(0, 1) MF_END();
    RD_A8(0, 1)
    if (more) stB(kt2, 0, 1);
    BARO(); MFQ(1, 1) MF_END();
    if (more) stA(kt2, 0, 1);
    BARO(); MFQ(1, 0)
    __builtin_amdgcn_s_setprio(0);
    if (more) { asm volatile("s_waitcnt vmcnt(6)" ::: "memory"); }
    else      { asm volatile("s_waitcnt vmcnt(0)" ::: "memory"); }
    __builtin_amdgcn_sched_barrier(0);
    __builtin_amdgcn_s_barrier();
    // ---- K-tile 2i+1 (buf1) ----
    RD_A8(65536, 0) RD_B4(65536, 0)
    if (more) stB(kt2, 0, 0);
    BARO(); MFQ(0, 0) MF_END();
    RD_B4(65536, 1)
    if (more) stA(2 * i + 3, 65536, 0);
    BARO(); MFQ(0, 1) MF_END();
    RD_A8(65536, 1)
    if (more) stB(2 * i + 3, 65536, 1);
    BARO(); MFQ(1, 1) MF_END();
    if (more) stA(2 * i + 3, 65536, 1);
    BARO(); MFQ(1, 0)
    __builtin_amdgcn_s_setprio(0);
    if (more) { asm volatile("s_waitcnt vmcnt(6)" ::: "memory"); }
    __builtin_amdgcn_sched_barrier(0);
    __builtin_amdgcn_s_barrier();
  }

  // epilogue
  #pragma unroll
  for (int mh = 0; mh < 2; ++mh)
  #pragma unroll
  for (int nh = 0; nh < 2; ++nh)
  #pragma unroll
  for (int n = 0; n < 2; ++n) {
    const int gn = bn * 256 + nh * 128 + wn * 32 + n * 16 + fr;
    const float bval = (EPI == 4) ? 0.f : bias[gn];
    #pragma unroll
    for (int m = 0; m < 4; ++m) {
      f32x4 d = acc[mh * 4 + m][nh * 2 + n];
      #pragma unroll
      for (int r = 0; r < 4; ++r) {
        const int gm = bm * 256 + mh * 128 + wm * 64 + m * 16 + lq * 4 + r;
        if (gm < M) {
          if (EPI == 0) {
            outb[(size_t)gm * ldo + gn] = f2b(d[r] + bval);
          } else if (EPI == 1) {
            float v0 = d[r] + bval;
            outb[(size_t)gm * ldo + gn] = f2b(v0 / (1.f + __expf(-1.702f * v0)));
          } else {
            outf[((size_t)bz * M + gm) * ldo + gn] = d[r];
          }
        }
      }
    }
  }
}

extern "C" void kernel_launch(void* const* d_in, const int* in_sizes, int n_in,
                              void* d_out, int out_size, void* d_ws, size_t ws_size,
                              hipStream_t stream)
{
  (void)in_sizes; (void)n_in; (void)out_size; (void)ws_size;
  const float* x_in  = (const float*)d_in[0];
  const float* attb  = (const float*)d_in[1];
  const float* ln1_g = (const float*)d_in[2];
  const float* ln1_b = (const float*)d_in[3];
  const float* in_w  = (const float*)d_in[4];
  const float* in_b  = (const float*)d_in[5];
  const float* out_w = (const float*)d_in[6];
  const float* out_b = (const float*)d_in[7];
  const float* ln2_g = (const float*)d_in[8];
  const float* ln2_b = (const float*)d_in[9];
  const float* fc1_w = (const float*)d_in[10];
  const float* fc1_b = (const float*)d_in[11];
  const float* fc2_w = (const float*)d_in[12];
  const float* fc2_b = (const float*)d_in[13];
  float* x = (float*)d_out;

  char* ws = (char*)d_ws;
  size_t off = 0;
  auto alloc = [&](size_t bytes) -> void* {
    void* p = ws + off; off += (bytes + 255) & ~(size_t)255; return p;
  };
  ushort* wIn   = (ushort*)alloc(2ull * 3072 * 1024 * 2);
  ushort* wOut  = (ushort*)alloc(2ull * 1024 * 1024 * 2);
  ushort* wF1   = (ushort*)alloc(2ull * 4096 * 1024 * 2);
  ushort* wF2   = (ushort*)alloc(2ull * 4096 * 1024 * 2);
  ushort* hbuf  = (ushort*)alloc((size_t)ROWS * 1024 * 2);
  ushort* qkv   = (ushort*)alloc((size_t)ROWS * 3072 * 2);
  ushort* vt    = (ushort*)alloc((size_t)8 * 1024 * 608 * 2);
  ushort* attn  = (ushort*)alloc((size_t)8 * 608 * 608 * 2);
  ushort* attnp = (ushort*)alloc((size_t)4 * 8 * 608 * 608 * 2);
  ushort* outlb = (ushort*)alloc((size_t)ROWS * 1024 * 2);
  float*  pbuf  = (float*)alloc((size_t)4 * ROWS * 1024 * 4);
  ushort* ubuf  = qkv;  // aliases qkv+vt region; both dead by MLP phase

  cvt4_kernel<<<(1572864 + 524288 + 2097152 + 2097152 + 255) / 256, 256, 0, stream>>>(
      in_w,  wIn,  1572864,
      out_w, wOut, 524288,
      fc1_w, wF1,  2097152,
      fc2_w, wF2,  2097152);
  ln_resid_kernel<0, true><<<ROWS, 256, 0, stream>>>(x_in, nullptr, nullptr,
      ln1_g, ln1_b, x, hbuf);

  for (int i = 0; i < 2; ++i) {
    gemm8<0><<<dim3(19, 12, 1), 512, 0, stream>>>(hbuf, 1024, ROWS,
        wIn + (size_t)i * 3072 * 1024, 1024,
        ROWS, 1024, in_b + i * 3072, qkv, nullptr, 3072);
    attn_kernel<<<dim3(37, 8, 4), 256, 0, stream>>>(qkv, attb + (size_t)i * 128 * 577 * 577, attnp);
    vt_kernel<<<dim3(19, 32, 8), 256, 0, stream>>>(qkv, vt);
    attn_combine<<<dim3(608, 8), 256, 0, stream>>>(attnp, attn);
    av_gemm<<<dim3(5, 8, 8), 256, 0, stream>>>(attn, 608, 577, (long)608 * 608,
        vt, 608, (long)1024 * 608, 577, 608, outlb, 1024);
    gemm8<4><<<dim3(19, 4, 2), 512, 0, stream>>>(outlb, 1024, ROWS,
        wOut + (size_t)i * 1024 * 1024, 1024,
        ROWS, 512, nullptr, nullptr, pbuf, 1024);
    ln_resid_kernel<2, true><<<ROWS, 256, 0, stream>>>(x, pbuf, out_b + i * 1024,
        ln2_g + i * 1024, ln2_b + i * 1024, x, hbuf);
    gemm8<1><<<dim3(19, 16, 1), 512, 0, stream>>>(hbuf, 1024, ROWS,
        wF1 + (size_t)i * 4096 * 1024, 1024,
        ROWS, 1024, fc1_b + i * 4096, ubuf, nullptr, 4096);
    gemm8<4><<<dim3(19, 4, 4), 512, 0, stream>>>(ubuf, 4096, ROWS,
        wF2 + (size_t)i * 4096 * 1024, 4096,
        ROWS, 1024, nullptr, nullptr, pbuf, 1024);
    if (i == 0) {
      ln_resid_kernel<4, true><<<ROWS, 256, 0, stream>>>(x, pbuf, fc2_b,
          ln1_g + 1024, ln1_b + 1024, x, hbuf);
    } else {
      ln_resid_kernel<4, false><<<ROWS, 256, 0, stream>>>(x, pbuf, fc2_b + 1024,
          nullptr, nullptr, x, nullptr);
    }
  }
}